// Round 1
// 9694.142 us; speedup vs baseline: 1.1202x; 1.1202x over previous
//
#include <hip/hip_runtime.h>
#include <math.h>

#define PITCH 72      // bank(col p, elem u) = (8p+u) mod 32: 4 slots by p mod 4,
                      // consecutive round-robin p's -> 2 lanes/bank = free (m136)
#define SW_BATCH 9
#define SW_SMALL 10
#define NPART 32
#define EPS2_ROT 1e-12f   // (1e-6)^2 : threshold compared on d^2

// ---- workspace float-offsets ----
#define OFF_ACCG 0
#define OFF_ACCT (NPART*4096)
#define OFF_BASE (2*NPART*4096)
#define SL_MNH  (OFF_BASE + 0*4096)
#define SL_MH   (OFF_BASE + 1*4096)
#define SL_WH   (OFF_BASE + 2*4096)
#define SL_P    (OFF_BASE + 3*4096)
#define SL_Q    (OFF_BASE + 4*4096)
#define SL_GH   (OFF_BASE + 5*4096)
#define SL_GNH  (OFF_BASE + 6*4096)
#define SL_MNH2 (OFF_BASE + 7*4096)
#define SL_WCH  (OFF_BASE + 8*4096)
#define OFF_VAR (OFF_BASE + 9*4096)
#define SL_SC   (OFF_BASE + 9*4096 + 1)

struct __align__(16) F4 { float v[4]; };

// Row-major pitch-72 storage. For a symmetric matrix, storage row k == column k,
// so Hestenes "column" ops are contiguous runs A[k*PITCH + r].
struct __align__(16) Smem {
  float S0[64*PITCH];
  float S1[64*PITCH];
  float w2[64];    // sigma^2 (= lambda^2) after hestenes
  float wc[64];    // recon coefficients f(lambda)/lambda^2
  float nrm[64];   // live column norms during hestenes
  float red[256];
  int flag;
};

// ---------- LDS <-> global (blockDim.x == 256), float4 path ----------
// e4 = float4 index 0..1023 ; row = e4>>4 ; col = 4*(e4&15)
// LDS banks: (8*row + col) mod 32 -> 8 segments per 4-bank cluster = optimal.
// Global: lane-consecutive 16B chunks = fully coalesced 1KB/wave.
__device__ __forceinline__ void g2s(float* dst, const float* __restrict__ src) {
  int t = threadIdx.x;
#pragma unroll
  for (int i = 0; i < 4; ++i) {
    int e4 = t + (i << 8);
    F4 vv = *(const F4*)&src[e4 * 4];
    *(F4*)&dst[(e4 >> 4) * PITCH + (e4 & 15) * 4] = vv;
  }
  __syncthreads();
}
__device__ __forceinline__ void g2s_scaled(float* dst, const float* __restrict__ src, float sc) {
  int t = threadIdx.x;
#pragma unroll
  for (int i = 0; i < 4; ++i) {
    int e4 = t + (i << 8);
    F4 vv = *(const F4*)&src[e4 * 4];
#pragma unroll
    for (int m = 0; m < 4; ++m) vv.v[m] *= sc;
    *(F4*)&dst[(e4 >> 4) * PITCH + (e4 & 15) * 4] = vv;
  }
  __syncthreads();
}
__device__ __forceinline__ void s2g(float* __restrict__ dst, const float* src) {
  int t = threadIdx.x;
#pragma unroll
  for (int i = 0; i < 4; ++i) {
    int e4 = t + (i << 8);
    F4 vv = *(const F4*)&src[(e4 >> 4) * PITCH + (e4 & 15) * 4];
    *(F4*)&dst[e4 * 4] = vv;
  }
  __syncthreads();
}

// ---------- 64x64 matmuls ----------
// MODE 0: S0 <- S1*S0 ; 1: S0 <- S0*S1 ; 2: S0 <- S0*S1^T ; 3: S0 <- S1*S1
// MODE 0/1/3: output tile rows {R0+16i} x cols {4*(t&15)+m}; both operands read
// as float4 (a along k, b along row) -> 8 ds_read_b128 per 4 k's (was 32 b32).
// MODE 2: b must read rows (J0+16m) along k; a 4-consecutive-col tile there maps
// every lane to one bank cluster, so MODE 2 keeps the old 16-strided col tile
// (b32 b-reads, same banks as before) and only vectorizes the a-side.
template<int MODE>
__device__ void mmX(Smem& sm) {
  int t = threadIdx.x;
  int R0 = t >> 4;
  if (MODE == 2) {
    int J0 = t & 15;
    float acc[4][4] = {};
    for (int kb = 0; kb < 64; kb += 4) {
      F4 a4[4];
#pragma unroll
      for (int i = 0; i < 4; ++i)
        a4[i] = *(const F4*)&sm.S0[(R0 + 16 * i) * PITCH + kb];
#pragma unroll
      for (int kk = 0; kk < 4; ++kk) {
        float b[4];
#pragma unroll
        for (int m = 0; m < 4; ++m) b[m] = sm.S1[(J0 + 16 * m) * PITCH + kb + kk];
#pragma unroll
        for (int i = 0; i < 4; ++i)
#pragma unroll
          for (int m = 0; m < 4; ++m) acc[i][m] = fmaf(a4[i].v[kk], b[m], acc[i][m]);
      }
    }
    __syncthreads();   // all reads done before in-place overwrite
#pragma unroll
    for (int i = 0; i < 4; ++i)
#pragma unroll
      for (int m = 0; m < 4; ++m)
        sm.S0[(R0 + 16 * i) * PITCH + J0 + 16 * m] = acc[i][m];
    __syncthreads();
  } else {
    int J = (t & 15) * 4;
    float acc[4][4] = {};
    for (int kb = 0; kb < 64; kb += 4) {
      F4 a4[4], b4[4];
#pragma unroll
      for (int i = 0; i < 4; ++i) {
        const float* L = (MODE == 0 || MODE == 3) ? sm.S1 : sm.S0;
        a4[i] = *(const F4*)&L[(R0 + 16 * i) * PITCH + kb];
      }
#pragma unroll
      for (int kk = 0; kk < 4; ++kk) {
        const float* Rp = (MODE == 0) ? sm.S0 : sm.S1;
        b4[kk] = *(const F4*)&Rp[(kb + kk) * PITCH + J];
      }
#pragma unroll
      for (int i = 0; i < 4; ++i)
#pragma unroll
        for (int kk = 0; kk < 4; ++kk)
#pragma unroll
          for (int m = 0; m < 4; ++m)
            acc[i][m] = fmaf(a4[i].v[kk], b4[kk].v[m], acc[i][m]);
    }
    __syncthreads();   // all reads done before in-place overwrite
#pragma unroll
    for (int i = 0; i < 4; ++i) {
      F4 o;
#pragma unroll
      for (int m = 0; m < 4; ++m) o.v[m] = acc[i][m];
      *(F4*)&sm.S0[(R0 + 16 * i) * PITCH + J] = o;
    }
    __syncthreads();
  }
}

// S1 <- sum_k wc[k] * S0row_k (x) S0row_k   (reads S0/wc, writes S1)
// b-side float4 (row-internal 4-chunk: banks (8k+4c4) -> 8 clusters, free);
// a-side stays b32 at {R0+16i} (4 addrs, 16-way broadcast, free);
// float4 C-write (8 segments/cluster = optimal).
__device__ void reconT(Smem& sm) {
  __syncthreads();   // wc visibility; prior S1 readers done
  int t = threadIdx.x;
  int R0 = t >> 4;
  int J = (t & 15) * 4;
  float acc[4][4] = {};
  for (int k = 0; k < 64; ++k) {
    float w = sm.wc[k];
    float a[4];
#pragma unroll
    for (int i = 0; i < 4; ++i) a[i] = w * sm.S0[k * PITCH + R0 + 16 * i];
    F4 b = *(const F4*)&sm.S0[k * PITCH + J];
#pragma unroll
    for (int i = 0; i < 4; ++i)
#pragma unroll
      for (int m = 0; m < 4; ++m) acc[i][m] = fmaf(a[i], b.v[m], acc[i][m]);
  }
#pragma unroll
  for (int i = 0; i < 4; ++i) {
    F4 o;
#pragma unroll
    for (int m = 0; m < 4; ++m) o.v[m] = acc[i][m];
    *(F4*)&sm.S1[(R0 + 16 * i) * PITCH + J] = o;
  }
  __syncthreads();
}

// Frobenius^2 of S0 (block reduction)
__device__ float frob2(Smem& sm) {
  int t = threadIdx.x;
  float s = 0.f;
#pragma unroll
  for (int i = 0; i < 4; ++i) {
    int e4 = t + (i << 8);
    F4 vv = *(const F4*)&sm.S0[(e4 >> 4) * PITCH + (e4 & 15) * 4];
#pragma unroll
    for (int m = 0; m < 4; ++m) s = fmaf(vv.v[m], vv.v[m], s);
  }
  sm.red[t] = s;
  __syncthreads();
  for (int o = 128; o; o >>= 1) { if (t < o) sm.red[t] += sm.red[t + o]; __syncthreads(); }
  float f = sm.red[0];
  __syncthreads();
  return f;
}

// ---------- one-sided (Hestenes) Jacobi, 64x64 symmetric ----------
// S0 in: symmetric matrix (storage row k == column k).
// S0 out: columns = lambda_k * u_k (as storage rows). sm.w2[k] = lambda_k^2.
// No eigenvector matrix needed. One barrier per round.
// Rotation params use raw HW approximations (v_rcp/v_sqrt/v_rsq, ~1 ulp):
// Jacobi is self-correcting, and the IEEE div/sqrt fixup sequences (~40 extra
// VALU instr/rotation under -O3 without fast-math) were pure issue overhead.
__device__ void hestenes(Smem& sm, int sweeps) {
  const int t = threadIdx.x;
  const int g = t >> 3;     // pair/group id 0..31 (8 lanes per group)
  const int u = t & 7;      // row-slice within group
  float* A = sm.S0;

  // initial column norms (cols g and g+32 per group)
  {
    float sa = 0.f, sb = 0.f;
#pragma unroll
    for (int i = 0; i < 8; ++i) {
      float va = A[g * PITCH + u + 8 * i];
      float vb = A[(g + 32) * PITCH + u + 8 * i];
      sa = fmaf(va, va, sa); sb = fmaf(vb, vb, sb);
    }
    sa += __shfl_xor(sa, 1); sa += __shfl_xor(sa, 2); sa += __shfl_xor(sa, 4);
    sb += __shfl_xor(sb, 1); sb += __shfl_xor(sb, 2); sb += __shfl_xor(sb, 4);
    if (u == 0) { sm.nrm[g] = sa; sm.nrm[g + 32] = sb; }
    if (t == 0) sm.flag = 0;
  }
  __syncthreads();

  for (int s = 0; s < sweeps; ++s) {
    for (int r = 0; r < 63; ++r) {
      // round-robin pairing (32 disjoint pairs per round)
      int p, q;
      if (g == 0) { p = 63; q = r; }
      else {
        int a = r + g;      if (a >= 63) a -= 63;
        int b = r + 63 - g; if (b >= 63) b -= 63;
        p = a; q = b;
      }
      const int bp = p * PITCH + u, bq = q * PITCH + u;
      float cp[8], cq[8];
#pragma unroll
      for (int i = 0; i < 8; ++i) { cp[i] = A[bp + 8 * i]; cq[i] = A[bq + 8 * i]; }
      float d = 0.f;
#pragma unroll
      for (int i = 0; i < 8; ++i) d = fmaf(cp[i], cq[i], d);
      d += __shfl_xor(d, 1); d += __shfl_xor(d, 2); d += __shfl_xor(d, 4);
      float dpp = sm.nrm[p], dqq = sm.nrm[q];
      if (d * d > EPS2_ROT * (dpp * dqq)) {   // group-uniform branch, sqrt-free
        float tau = (dqq - dpp) * (0.5f * __builtin_amdgcn_rcpf(d));
        float tt = __builtin_amdgcn_rcpf(fabsf(tau) +
                                         __builtin_amdgcn_sqrtf(fmaf(tau, tau, 1.f)));
        if (tau < 0.f) tt = -tt;
        float c = __builtin_amdgcn_rsqf(fmaf(tt, tt, 1.f));
        float s_ = tt * c;
#pragma unroll
        for (int i = 0; i < 8; ++i) {
          A[bp + 8 * i] = c * cp[i] - s_ * cq[i];
          A[bq + 8 * i] = s_ * cp[i] + c * cq[i];
        }
        if (u == 0) {
          float td = tt * d;
          sm.nrm[p] = dpp - td;    // exact Jacobi diagonal update
          sm.nrm[q] = dqq + td;
          sm.flag = 1;             // benign race
        }
      }
      __syncthreads();
    }
    int f = sm.flag;
    __syncthreads();
    if (f == 0) break;
    if (t == 0) sm.flag = 0;
    __syncthreads();
  }

  // exact final norms -> w2 = lambda^2
  {
    float sa = 0.f, sb = 0.f;
#pragma unroll
    for (int i = 0; i < 8; ++i) {
      float va = A[g * PITCH + u + 8 * i];
      float vb = A[(g + 32) * PITCH + u + 8 * i];
      sa = fmaf(va, va, sa); sb = fmaf(vb, vb, sb);
    }
    sa += __shfl_xor(sa, 1); sa += __shfl_xor(sa, 2); sa += __shfl_xor(sa, 4);
    sb += __shfl_xor(sb, 1); sb += __shfl_xor(sb, 2); sb += __shfl_xor(sb, 4);
    if (u == 0) { sm.w2[g] = sa; sm.w2[g + 32] = sb; }
  }
  __syncthreads();
}

// ============================ kernels ============================

__global__ __launch_bounds__(256) void kzero(float* ws) {
  int i = blockIdx.x * 256 + threadIdx.x;
  if (i < OFF_BASE) ws[i] = 0.f;
  if (i == 0) ws[OFF_VAR] = 0.f;
}

// Mnh/Mh/Wh/Wc-eig -> P = Wc^{-1/2} Wh, Q = Mh Wc^{1/2}
__global__ __launch_bounds__(256, 4) void kprep(const float* __restrict__ weight,
                                                const float* __restrict__ M,
                                                float* ws) {
  __shared__ Smem sm;
  int t = threadIdx.x;
  g2s(sm.S0, M);
  hestenes(sm, SW_SMALL);
  if (t < 64) sm.wc[t] = powf(fmaxf(sm.w2[t], 1e-12f), -1.25f);  // lambda^{-1/2-2}
  reconT(sm); s2g(ws + SL_MNH, sm.S1);
  if (t < 64) sm.wc[t] = powf(fmaxf(sm.w2[t], 1e-12f), -0.75f);  // lambda^{1/2-2}
  reconT(sm); s2g(ws + SL_MH, sm.S1);

  g2s(sm.S0, weight);
  hestenes(sm, SW_SMALL);
  if (t < 64) sm.wc[t] = powf(fmaxf(sm.w2[t], 1e-12f), -0.75f);
  reconT(sm); s2g(ws + SL_WH, sm.S1);        // S1 = Wh

  g2s(sm.S0, ws + SL_MNH);
  mmX<1>(sm);                                 // S0 = Mnh*Wh
  g2s(sm.S1, ws + SL_MNH);
  mmX<1>(sm);                                 // S0 = Wc
  hestenes(sm, SW_SMALL);
  if (t < 64) sm.wc[t] = powf(fmaxf(sm.w2[t], 1e-12f), -0.75f);
  reconT(sm); s2g(ws + SL_WCH, sm.S1);        // Wc^{1/2}
  if (t < 64) sm.wc[t] = powf(fmaxf(sm.w2[t], 1e-12f), -1.25f);
  reconT(sm);                                 // S1 = Wc^{-1/2}
  g2s(sm.S0, ws + SL_WH);
  mmX<0>(sm);                                 // S0 = Wcnh*Wh = P
  s2g(ws + SL_P, sm.S0);
  g2s(sm.S0, ws + SL_WCH);
  g2s(sm.S1, ws + SL_MH);
  mmX<0>(sm);                                 // S0 = Mh*Wch = Q
  s2g(ws + SL_Q, sm.S0);
}

// Xc_i = Mnh sqrt(X_i) Mnh -> out ; accumulate sum(Xc)
__global__ __launch_bounds__(256, 4) void k1(const float* __restrict__ X,
                                             float* __restrict__ out, float* ws) {
  __shared__ Smem sm;
  int t = threadIdx.x;
  size_t b = blockIdx.x;
  g2s(sm.S0, X + b * 4096);
  hestenes(sm, SW_BATCH);
  g2s(sm.S1, ws + SL_MNH);
  mmX<1>(sm);                                 // S0 rows = lam_k (Mnh u_k)^T
  if (t < 64) sm.wc[t] = powf(fmaxf(sm.w2[t], 1e-12f), -0.75f);  // sqrt: lam^{1/2-2}
  reconT(sm);                                 // S1 = Xc
  float* Xc = out + b * 4096;
  float* acc = ws + OFF_ACCG + (size_t)(blockIdx.x & (NPART - 1)) * 4096;
#pragma unroll
  for (int i = 0; i < 4; ++i) {
    int e4 = t + (i << 8);
    F4 vv = *(const F4*)&sm.S1[(e4 >> 4) * PITCH + (e4 & 15) * 4];
    *(F4*)&Xc[e4 * 4] = vv;
#pragma unroll
    for (int m = 0; m < 4; ++m) atomicAdd(acc + e4 * 4 + m, vv.v[m]);
  }
}

// G0 = mean(Xc); eig -> G0h, G0nh
__global__ __launch_bounds__(256, 4) void ksmall2(float* ws, float invB) {
  __shared__ Smem sm;
  int t = threadIdx.x;
#pragma unroll
  for (int i = 0; i < 4; ++i) {
    int e4 = t + (i << 8);
    F4 sum = {{0.f, 0.f, 0.f, 0.f}};
    for (int p = 0; p < NPART; ++p) {
      F4 vv = *(const F4*)&ws[OFF_ACCG + p * 4096 + e4 * 4];
#pragma unroll
      for (int m = 0; m < 4; ++m) sum.v[m] += vv.v[m];
    }
#pragma unroll
    for (int m = 0; m < 4; ++m) sum.v[m] *= invB;
    *(F4*)&sm.S0[(e4 >> 4) * PITCH + (e4 & 15) * 4] = sum;
  }
  __syncthreads();
  hestenes(sm, SW_SMALL);
  if (t < 64) sm.wc[t] = powf(fmaxf(sm.w2[t], 1e-12f), -0.75f);
  reconT(sm); s2g(ws + SL_GH, sm.S1);
  if (t < 64) sm.wc[t] = powf(fmaxf(sm.w2[t], 1e-12f), -1.25f);
  reconT(sm); s2g(ws + SL_GNH, sm.S1);
}

// accumulate sum_i log(G0nh Xc_i G0nh)
__global__ __launch_bounds__(256, 4) void k2(const float* __restrict__ XcBuf, float* ws) {
  __shared__ Smem sm;
  int t = threadIdx.x;
  size_t b = blockIdx.x;
  g2s(sm.S0, XcBuf + b * 4096);
  g2s(sm.S1, ws + SL_GNH);
  mmX<1>(sm);                                 // Xc*Gnh
  mmX<0>(sm);                                 // Gnh*Xc*Gnh
  hestenes(sm, SW_BATCH);
  if (t < 64) {
    float s2 = fmaxf(sm.w2[t], 1e-12f);
    sm.wc[t] = 0.5f * logf(s2) / s2;          // log(lam)/lam^2
  }
  reconT(sm);                                 // S1 = log(.)
  float* acc = ws + OFF_ACCT + (size_t)(blockIdx.x & (NPART - 1)) * 4096;
#pragma unroll
  for (int i = 0; i < 4; ++i) {
    int e4 = t + (i << 8);
    F4 vv = *(const F4*)&sm.S1[(e4 >> 4) * PITCH + (e4 & 15) * 4];
#pragma unroll
    for (int m = 0; m < 4; ++m) atomicAdd(acc + e4 * 4 + m, vv.v[m]);
  }
}

// Tbar = mean ; mean_G = G0h exp(Tbar) G0h ; mnh = mean_G^{-1/2}
__global__ __launch_bounds__(256, 4) void ksmall3(float* ws, float invB) {
  __shared__ Smem sm;
  int t = threadIdx.x;
#pragma unroll
  for (int i = 0; i < 4; ++i) {
    int e4 = t + (i << 8);
    F4 sum = {{0.f, 0.f, 0.f, 0.f}};
    for (int p = 0; p < NPART; ++p) {
      F4 vv = *(const F4*)&ws[OFF_ACCT + p * 4096 + e4 * 4];
#pragma unroll
      for (int m = 0; m < 4; ++m) sum.v[m] += vv.v[m];
    }
#pragma unroll
    for (int m = 0; m < 4; ++m) sum.v[m] *= invB;
    *(F4*)&sm.S0[(e4 >> 4) * PITCH + (e4 & 15) * 4] = sum;
  }
  __syncthreads();
  // exp of symmetric INDEFINITE Tbar: shift to SPD first
  float mu = sqrtf(frob2(sm)) + 1e-3f;
  if (t < 64) sm.S0[t * PITCH + t] += mu;
  __syncthreads();
  hestenes(sm, SW_SMALL);
  if (t < 64) {
    float s2 = fmaxf(sm.w2[t], 1e-12f);
    sm.wc[t] = expf(sqrtf(s2) - mu) / s2;
  }
  reconT(sm);                                 // S1 = E = exp(Tbar)
  g2s(sm.S0, ws + SL_GH);
  mmX<1>(sm);                                 // Gh*E
  g2s(sm.S1, ws + SL_GH);
  mmX<1>(sm);                                 // mean_G
  hestenes(sm, SW_SMALL);
  if (t < 64) sm.wc[t] = powf(fmaxf(sm.w2[t], 1e-12f), -1.25f);
  reconT(sm); s2g(ws + SL_MNH2, sm.S1);
}

// T_i = log(mnh Xc_i mnh) (overwrites Xc in buf) ; accumulate ||T||_F^2
__global__ __launch_bounds__(256, 4) void k3(float* __restrict__ buf, float* ws) {
  __shared__ Smem sm;
  int t = threadIdx.x;
  size_t b = blockIdx.x;
  g2s(sm.S0, buf + b * 4096);
  g2s(sm.S1, ws + SL_MNH2);
  mmX<1>(sm);
  mmX<0>(sm);
  hestenes(sm, SW_BATCH);
  if (t < 64) {
    float s2 = fmaxf(sm.w2[t], 1e-12f);
    sm.wc[t] = 0.5f * logf(s2) / s2;
  }
  reconT(sm);                                 // S1 = T
  float ssq = 0.f;
  float* Tg = buf + b * 4096;
#pragma unroll
  for (int i = 0; i < 4; ++i) {
    int e4 = t + (i << 8);
    F4 vv = *(const F4*)&sm.S1[(e4 >> 4) * PITCH + (e4 & 15) * 4];
    *(F4*)&Tg[e4 * 4] = vv;
#pragma unroll
    for (int m = 0; m < 4; ++m) ssq = fmaf(vv.v[m], vv.v[m], ssq);
  }
  sm.red[t] = ssq;
  __syncthreads();
  for (int o = 128; o; o >>= 1) { if (t < o) sm.red[t] += sm.red[t + o]; __syncthreads(); }
  if (t == 0) atomicAdd(ws + OFF_VAR, sm.red[0]);
}

__global__ void kscale(float* ws, const float* __restrict__ shift, float invB) {
  if (threadIdx.x == 0 && blockIdx.x == 0) {
    float var = ws[OFF_VAR] * invB;
    ws[SL_SC] = shift[0] / sqrtf(var + 1e-5f);
  }
}

// Y_i = (Q exp(scale * P T_i P^T) Q^T)^2 -> buf
__global__ __launch_bounds__(256, 4) void k4(float* __restrict__ buf, float* ws) {
  __shared__ Smem sm;
  int t = threadIdx.x;
  size_t b = blockIdx.x;
  float sc = ws[SL_SC];
  g2s_scaled(sm.S0, buf + b * 4096, sc);      // scale*T
  g2s(sm.S1, ws + SL_P);
  mmX<0>(sm);                                 // P*(scT)
  mmX<2>(sm);                                 // P*(scT)*P^T  (symmetric indefinite)
  float mu = sqrtf(frob2(sm)) + 1e-3f;
  if (t < 64) sm.S0[t * PITCH + t] += mu;
  __syncthreads();
  hestenes(sm, SW_BATCH);
  if (t < 64) {
    float s2 = fmaxf(sm.w2[t], 1e-12f);
    sm.wc[t] = expf(sqrtf(s2) - mu) / s2;
  }
  g2s(sm.S1, ws + SL_Q);
  mmX<2>(sm);                                 // rows = lam (Q u)^T
  reconT(sm);                                 // S1 = Z = Q E Q^T
  mmX<3>(sm);                                 // S0 = Z*Z
  s2g(buf + b * 4096, sm.S0);
}

extern "C" void kernel_launch(void* const* d_in, const int* in_sizes, int n_in,
                              void* d_out, int out_size, void* d_ws, size_t ws_size,
                              hipStream_t stream) {
  const float* X      = (const float*)d_in[0];
  const float* weight = (const float*)d_in[1];
  const float* M      = (const float*)d_in[2];
  const float* shift  = (const float*)d_in[3];
  float* out = (float*)d_out;
  float* ws  = (float*)d_ws;
  int B = in_sizes[0] / 4096;      // 4096 matrices of 64x64
  float invB = 1.f / (float)B;

  hipLaunchKernelGGL(kzero,   dim3(OFF_BASE / 256), dim3(256), 0, stream, ws);
  hipLaunchKernelGGL(kprep,   dim3(1), dim3(256), 0, stream, weight, M, ws);
  hipLaunchKernelGGL(k1,      dim3(B), dim3(256), 0, stream, X, out, ws);
  hipLaunchKernelGGL(ksmall2, dim3(1), dim3(256), 0, stream, ws, invB);
  hipLaunchKernelGGL(k2,      dim3(B), dim3(256), 0, stream, out, ws);
  hipLaunchKernelGGL(ksmall3, dim3(1), dim3(256), 0, stream, ws, invB);
  hipLaunchKernelGGL(k3,      dim3(B), dim3(256), 0, stream, out, ws);
  hipLaunchKernelGGL(kscale,  dim3(1), dim3(64), 0, stream, ws, shift, invB);
  hipLaunchKernelGGL(k4,      dim3(B), dim3(256), 0, stream, out, ws);
}

// Round 2
// 9168.394 us; speedup vs baseline: 1.1844x; 1.0573x over previous
//
#include <hip/hip_runtime.h>
#include <math.h>

#define PITCH 72      // old layout (small kernels only)
#define NP 68         // new pitch: word(row r, col c) = 68r+c ; bank = (4r+c) mod 32
#define SW_BATCH 12
#define SW_SMALL 10
#define NPART 32
#define EPS2_ROT 1e-12f   // (1e-6)^2 : threshold compared on d^2

// ---- workspace float-offsets ----
#define OFF_ACCG 0
#define OFF_ACCT (NPART*4096)
#define OFF_BASE (2*NPART*4096)
#define SL_MNH  (OFF_BASE + 0*4096)
#define SL_MH   (OFF_BASE + 1*4096)
#define SL_WH   (OFF_BASE + 2*4096)
#define SL_P    (OFF_BASE + 3*4096)
#define SL_Q    (OFF_BASE + 4*4096)
#define SL_GH   (OFF_BASE + 5*4096)
#define SL_GNH  (OFF_BASE + 6*4096)
#define SL_MNH2 (OFF_BASE + 7*4096)
#define SL_WCH  (OFF_BASE + 8*4096)
#define OFF_VAR (OFF_BASE + 9*4096)
#define SL_SC   (OFF_BASE + 9*4096 + 1)

struct __align__(16) F4 { float v[4]; };

// ======================================================================
// OLD infrastructure (PITCH 72) — used only by the 1-block small kernels
// ======================================================================
struct __align__(16) Smem {
  float S0[64*PITCH];
  float S1[64*PITCH];
  float w2[64];
  float wc[64];
  float nrm[64];
  float red[256];
  int flag;
};

__device__ __forceinline__ void g2s(float* dst, const float* __restrict__ src) {
  int t = threadIdx.x;
#pragma unroll
  for (int i = 0; i < 4; ++i) {
    int e4 = t + (i << 8);
    F4 vv = *(const F4*)&src[e4 * 4];
    *(F4*)&dst[(e4 >> 4) * PITCH + (e4 & 15) * 4] = vv;
  }
  __syncthreads();
}
__device__ __forceinline__ void s2g(float* __restrict__ dst, const float* src) {
  int t = threadIdx.x;
#pragma unroll
  for (int i = 0; i < 4; ++i) {
    int e4 = t + (i << 8);
    F4 vv = *(const F4*)&src[(e4 >> 4) * PITCH + (e4 & 15) * 4];
    *(F4*)&dst[e4 * 4] = vv;
  }
  __syncthreads();
}

template<int MODE>   // 0: S0<-S1*S0 ; 1: S0<-S0*S1
__device__ void mmX(Smem& sm) {
  int t = threadIdx.x;
  int R0 = t >> 4;
  int J = (t & 15) * 4;
  float acc[4][4] = {};
  for (int kb = 0; kb < 64; kb += 4) {
    F4 a4[4], b4[4];
#pragma unroll
    for (int i = 0; i < 4; ++i) {
      const float* L = (MODE == 0) ? sm.S1 : sm.S0;
      a4[i] = *(const F4*)&L[(R0 + 16 * i) * PITCH + kb];
    }
#pragma unroll
    for (int kk = 0; kk < 4; ++kk) {
      const float* Rp = (MODE == 0) ? sm.S0 : sm.S1;
      b4[kk] = *(const F4*)&Rp[(kb + kk) * PITCH + J];
    }
#pragma unroll
    for (int i = 0; i < 4; ++i)
#pragma unroll
      for (int kk = 0; kk < 4; ++kk)
#pragma unroll
        for (int m = 0; m < 4; ++m)
          acc[i][m] = fmaf(a4[i].v[kk], b4[kk].v[m], acc[i][m]);
  }
  __syncthreads();
#pragma unroll
  for (int i = 0; i < 4; ++i) {
    F4 o;
#pragma unroll
    for (int m = 0; m < 4; ++m) o.v[m] = acc[i][m];
    *(F4*)&sm.S0[(R0 + 16 * i) * PITCH + J] = o;
  }
  __syncthreads();
}

__device__ void reconT(Smem& sm) {
  __syncthreads();
  int t = threadIdx.x;
  int R0 = t >> 4;
  int J = (t & 15) * 4;
  float acc[4][4] = {};
  for (int k = 0; k < 64; ++k) {
    float w = sm.wc[k];
    float a[4];
#pragma unroll
    for (int i = 0; i < 4; ++i) a[i] = w * sm.S0[k * PITCH + R0 + 16 * i];
    F4 b = *(const F4*)&sm.S0[k * PITCH + J];
#pragma unroll
    for (int i = 0; i < 4; ++i)
#pragma unroll
      for (int m = 0; m < 4; ++m) acc[i][m] = fmaf(a[i], b.v[m], acc[i][m]);
  }
#pragma unroll
  for (int i = 0; i < 4; ++i) {
    F4 o;
#pragma unroll
    for (int m = 0; m < 4; ++m) o.v[m] = acc[i][m];
    *(F4*)&sm.S1[(R0 + 16 * i) * PITCH + J] = o;
  }
  __syncthreads();
}

__device__ float frob2(Smem& sm) {
  int t = threadIdx.x;
  float s = 0.f;
#pragma unroll
  for (int i = 0; i < 4; ++i) {
    int e4 = t + (i << 8);
    F4 vv = *(const F4*)&sm.S0[(e4 >> 4) * PITCH + (e4 & 15) * 4];
#pragma unroll
    for (int m = 0; m < 4; ++m) s = fmaf(vv.v[m], vv.v[m], s);
  }
  sm.red[t] = s;
  __syncthreads();
  for (int o = 128; o; o >>= 1) { if (t < o) sm.red[t] += sm.red[t + o]; __syncthreads(); }
  float f = sm.red[0];
  __syncthreads();
  return f;
}

__device__ void hestenes(Smem& sm, int sweeps) {
  const int t = threadIdx.x;
  const int g = t >> 3;
  const int u = t & 7;
  float* A = sm.S0;
  {
    float sa = 0.f, sb = 0.f;
#pragma unroll
    for (int i = 0; i < 8; ++i) {
      float va = A[g * PITCH + u + 8 * i];
      float vb = A[(g + 32) * PITCH + u + 8 * i];
      sa = fmaf(va, va, sa); sb = fmaf(vb, vb, sb);
    }
    sa += __shfl_xor(sa, 1); sa += __shfl_xor(sa, 2); sa += __shfl_xor(sa, 4);
    sb += __shfl_xor(sb, 1); sb += __shfl_xor(sb, 2); sb += __shfl_xor(sb, 4);
    if (u == 0) { sm.nrm[g] = sa; sm.nrm[g + 32] = sb; }
    if (t == 0) sm.flag = 0;
  }
  __syncthreads();

  for (int s = 0; s < sweeps; ++s) {
    for (int r = 0; r < 63; ++r) {
      int p, q;
      if (g == 0) { p = 63; q = r; }
      else {
        int a = r + g;      if (a >= 63) a -= 63;
        int b = r + 63 - g; if (b >= 63) b -= 63;
        p = a; q = b;
      }
      const int bp = p * PITCH + u, bq = q * PITCH + u;
      float cp[8], cq[8];
#pragma unroll
      for (int i = 0; i < 8; ++i) { cp[i] = A[bp + 8 * i]; cq[i] = A[bq + 8 * i]; }
      float d = 0.f;
#pragma unroll
      for (int i = 0; i < 8; ++i) d = fmaf(cp[i], cq[i], d);
      d += __shfl_xor(d, 1); d += __shfl_xor(d, 2); d += __shfl_xor(d, 4);
      float dpp = sm.nrm[p], dqq = sm.nrm[q];
      if (d * d > EPS2_ROT * (dpp * dqq)) {
        float tau = (dqq - dpp) * (0.5f * __builtin_amdgcn_rcpf(d));
        float tt = __builtin_amdgcn_rcpf(fabsf(tau) +
                                         __builtin_amdgcn_sqrtf(fmaf(tau, tau, 1.f)));
        if (tau < 0.f) tt = -tt;
        float c = __builtin_amdgcn_rsqf(fmaf(tt, tt, 1.f));
        float s_ = tt * c;
#pragma unroll
        for (int i = 0; i < 8; ++i) {
          A[bp + 8 * i] = c * cp[i] - s_ * cq[i];
          A[bq + 8 * i] = s_ * cp[i] + c * cq[i];
        }
        if (u == 0) {
          float td = tt * d;
          sm.nrm[p] = dpp - td;
          sm.nrm[q] = dqq + td;
          sm.flag = 1;
        }
      }
      __syncthreads();
    }
    int f = sm.flag;
    __syncthreads();
    if (f == 0) break;
    if (t == 0) sm.flag = 0;
    __syncthreads();
  }

  {
    float sa = 0.f, sb = 0.f;
#pragma unroll
    for (int i = 0; i < 8; ++i) {
      float va = A[g * PITCH + u + 8 * i];
      float vb = A[(g + 32) * PITCH + u + 8 * i];
      sa = fmaf(va, va, sa); sb = fmaf(vb, vb, sb);
    }
    sa += __shfl_xor(sa, 1); sa += __shfl_xor(sa, 2); sa += __shfl_xor(sa, 4);
    sb += __shfl_xor(sb, 1); sb += __shfl_xor(sb, 2); sb += __shfl_xor(sb, 4);
    if (u == 0) { sm.w2[g] = sa; sm.w2[g + 32] = sb; }
  }
  __syncthreads();
}

// ======================================================================
// NEW infrastructure (pitch 68) — batch kernels, 4 matrices per block
// ======================================================================
struct __align__(16) SmemK {      // k1,k2,k3 : 36.1 KB
  float A[64*NP];
  float Bop[64*NP];
  float wc[64];
  float red[256];
};
struct __align__(16) SmemK4 {     // k4 : 52.3 KB
  float A[64*NP];
  float P[64*NP];
  float Q[64*NP];
  float wc[64];
  float red[256];
};

__device__ __forceinline__ void g2s68(float* dst, const float* __restrict__ src) {
  int t = threadIdx.x;
#pragma unroll
  for (int i = 0; i < 4; ++i) {
    int e4 = t + (i << 8);
    F4 vv = *(const F4*)&src[e4 * 4];
    *(F4*)&dst[(e4 >> 4) * NP + (e4 & 15) * 4] = vv;
  }
  __syncthreads();
}
__device__ __forceinline__ void g2s68s(float* dst, const float* __restrict__ src, float sc) {
  int t = threadIdx.x;
#pragma unroll
  for (int i = 0; i < 4; ++i) {
    int e4 = t + (i << 8);
    F4 vv = *(const F4*)&src[e4 * 4];
#pragma unroll
    for (int m = 0; m < 4; ++m) vv.v[m] *= sc;
    *(F4*)&dst[(e4 >> 4) * NP + (e4 & 15) * 4] = vv;
  }
  __syncthreads();
}

// MODE 0: A <- Bo*A ; 1: A <- A*Bo ; 2: A <- A*Bo^T   (all in-place on A)
template<int MODE>
__device__ void mm68(float* A, const float* Bo) {
  int t = threadIdx.x;
  int R0 = t >> 4;
  if (MODE == 2) {
    int J0 = t & 15;
    float acc[4][4] = {};
    for (int kb = 0; kb < 64; kb += 4) {
      F4 a4[4];
#pragma unroll
      for (int i = 0; i < 4; ++i) a4[i] = *(const F4*)&A[(R0 + 16 * i) * NP + kb];
#pragma unroll
      for (int kk = 0; kk < 4; ++kk) {
        float b[4];
#pragma unroll
        for (int m = 0; m < 4; ++m) b[m] = Bo[(J0 + 16 * m) * NP + kb + kk];
#pragma unroll
        for (int i = 0; i < 4; ++i)
#pragma unroll
          for (int m = 0; m < 4; ++m) acc[i][m] = fmaf(a4[i].v[kk], b[m], acc[i][m]);
      }
    }
    __syncthreads();
#pragma unroll
    for (int i = 0; i < 4; ++i)
#pragma unroll
      for (int m = 0; m < 4; ++m)
        A[(R0 + 16 * i) * NP + J0 + 16 * m] = acc[i][m];
    __syncthreads();
  } else {
    int J = (t & 15) * 4;
    float acc[4][4] = {};
    for (int kb = 0; kb < 64; kb += 4) {
      F4 a4[4], b4[4];
#pragma unroll
      for (int i = 0; i < 4; ++i) {
        const float* L = (MODE == 0) ? Bo : A;
        a4[i] = *(const F4*)&L[(R0 + 16 * i) * NP + kb];
      }
#pragma unroll
      for (int kk = 0; kk < 4; ++kk) {
        const float* Rp = (MODE == 0) ? A : Bo;
        b4[kk] = *(const F4*)&Rp[(kb + kk) * NP + J];
      }
#pragma unroll
      for (int i = 0; i < 4; ++i)
#pragma unroll
        for (int kk = 0; kk < 4; ++kk)
#pragma unroll
          for (int m = 0; m < 4; ++m)
            acc[i][m] = fmaf(a4[i].v[kk], b4[kk].v[m], acc[i][m]);
    }
    __syncthreads();
#pragma unroll
    for (int i = 0; i < 4; ++i) {
      F4 o;
#pragma unroll
      for (int m = 0; m < 4; ++m) o.v[m] = acc[i][m];
      *(F4*)&A[(R0 + 16 * i) * NP + J] = o;
    }
    __syncthreads();
  }
}

__device__ float frob68(const float* A, float* red) {
  int t = threadIdx.x;
  float s = 0.f;
#pragma unroll
  for (int i = 0; i < 4; ++i) {
    int e4 = t + (i << 8);
    F4 vv = *(const F4*)&A[(e4 >> 4) * NP + (e4 & 15) * 4];
#pragma unroll
    for (int m = 0; m < 4; ++m) s = fmaf(vv.v[m], vv.v[m], s);
  }
  red[t] = s;
  __syncthreads();
  for (int o = 128; o; o >>= 1) { if (t < o) red[t] += red[t + o]; __syncthreads(); }
  float f = red[0];
  __syncthreads();
  return f;
}

// Z*Z -> global (row-major 64x64), reads Z (pitch 68), no LDS writes
__device__ void msq_store(const float* Z, float* __restrict__ gout) {
  int t = threadIdx.x;
  int R0 = t >> 4;
  int J = (t & 15) * 4;
  float acc[4][4] = {};
  for (int kb = 0; kb < 64; kb += 4) {
    F4 a4[4], b4[4];
#pragma unroll
    for (int i = 0; i < 4; ++i) a4[i] = *(const F4*)&Z[(R0 + 16 * i) * NP + kb];
#pragma unroll
    for (int kk = 0; kk < 4; ++kk) b4[kk] = *(const F4*)&Z[(kb + kk) * NP + J];
#pragma unroll
    for (int i = 0; i < 4; ++i)
#pragma unroll
      for (int kk = 0; kk < 4; ++kk)
#pragma unroll
        for (int m = 0; m < 4; ++m)
          acc[i][m] = fmaf(a4[i].v[kk], b4[kk].v[m], acc[i][m]);
  }
#pragma unroll
  for (int i = 0; i < 4; ++i) {
    F4 o;
#pragma unroll
    for (int m = 0; m < 4; ++m) o.v[m] = acc[i][m];
    *(F4*)&gout[(R0 + 16 * i) * 64 + J] = o;
  }
}

// ---------- register-resident wave-synchronous one-sided Jacobi ----------
// lane l holds column l (= row l of the symmetric input) in own[64].
// XOR ordering: round m pairs lane l with lane l^m (m=1..63) — each column
// pair exactly once per sweep. Both lanes of a pair compute bitwise-identical
// d / rotation params (products commute), so no reduce/broadcast is needed.
// No LDS, no barriers; convergence via wave-level __any.
__device__ __forceinline__ void hestenes_reg(float (&own)[64], float& w2out, int sweeps) {
  const int lane = threadIdx.x & 63;
  float nrm = 0.f;
#pragma unroll
  for (int i = 0; i < 64; ++i) nrm = fmaf(own[i], own[i], nrm);

  for (int s = 0; s < sweeps; ++s) {
    bool any = false;
    for (int m = 1; m < 64; ++m) {
      float pv[64];
#pragma unroll
      for (int i = 0; i < 64; ++i) pv[i] = __shfl_xor(own[i], m);
      float d0 = 0.f, d1 = 0.f, d2 = 0.f, d3 = 0.f;
#pragma unroll
      for (int i = 0; i < 64; i += 4) {
        d0 = fmaf(own[i + 0], pv[i + 0], d0);
        d1 = fmaf(own[i + 1], pv[i + 1], d1);
        d2 = fmaf(own[i + 2], pv[i + 2], d2);
        d3 = fmaf(own[i + 3], pv[i + 3], d3);
      }
      float d = (d0 + d1) + (d2 + d3);
      float pn = __shfl_xor(nrm, m);
      if (d * d > EPS2_ROT * (nrm * pn)) {     // pair-uniform (bitwise-symmetric)
        any = true;
        bool lo = lane < (lane ^ m);           // exactly one lane of the pair
        float dpp = lo ? nrm : pn;
        float dqq = lo ? pn : nrm;
        float tau = (dqq - dpp) * (0.5f * __builtin_amdgcn_rcpf(d));
        float tt = __builtin_amdgcn_rcpf(fabsf(tau) +
                                         __builtin_amdgcn_sqrtf(fmaf(tau, tau, 1.f)));
        if (tau < 0.f) tt = -tt;
        float c = __builtin_amdgcn_rsqf(fmaf(tt, tt, 1.f));
        float s_ = tt * c;
        float sg = lo ? -s_ : s_;              // lo: c*p - s*q ; hi: c*q + s*p
#pragma unroll
        for (int i = 0; i < 64; ++i) own[i] = fmaf(sg, pv[i], c * own[i]);
        float td = tt * d;
        nrm += lo ? -td : td;                  // exact Jacobi diagonal update
      }
    }
    if (!__any((int)any)) break;
  }
  float w = 0.f;
#pragma unroll
  for (int i = 0; i < 64; ++i) w = fmaf(own[i], own[i], w);
  w2out = w;
}

// ============================ kernels ============================

__global__ __launch_bounds__(256) void kzero(float* ws) {
  int i = blockIdx.x * 256 + threadIdx.x;
  if (i < OFF_BASE) ws[i] = 0.f;
  if (i == 0) ws[OFF_VAR] = 0.f;
}

// Mnh/Mh/Wh/Wc-eig -> P = Wc^{-1/2} Wh, Q = Mh Wc^{1/2}   (unchanged, old path)
__global__ __launch_bounds__(256, 4) void kprep(const float* __restrict__ weight,
                                                const float* __restrict__ M,
                                                float* ws) {
  __shared__ Smem sm;
  int t = threadIdx.x;
  g2s(sm.S0, M);
  hestenes(sm, SW_SMALL);
  if (t < 64) sm.wc[t] = powf(fmaxf(sm.w2[t], 1e-12f), -1.25f);
  reconT(sm); s2g(ws + SL_MNH, sm.S1);
  if (t < 64) sm.wc[t] = powf(fmaxf(sm.w2[t], 1e-12f), -0.75f);
  reconT(sm); s2g(ws + SL_MH, sm.S1);

  g2s(sm.S0, weight);
  hestenes(sm, SW_SMALL);
  if (t < 64) sm.wc[t] = powf(fmaxf(sm.w2[t], 1e-12f), -0.75f);
  reconT(sm); s2g(ws + SL_WH, sm.S1);

  g2s(sm.S0, ws + SL_MNH);
  mmX<1>(sm);
  g2s(sm.S1, ws + SL_MNH);
  mmX<1>(sm);
  hestenes(sm, SW_SMALL);
  if (t < 64) sm.wc[t] = powf(fmaxf(sm.w2[t], 1e-12f), -0.75f);
  reconT(sm); s2g(ws + SL_WCH, sm.S1);
  if (t < 64) sm.wc[t] = powf(fmaxf(sm.w2[t], 1e-12f), -1.25f);
  reconT(sm);
  g2s(sm.S0, ws + SL_WH);
  mmX<0>(sm);
  s2g(ws + SL_P, sm.S0);
  g2s(sm.S0, ws + SL_WCH);
  g2s(sm.S1, ws + SL_MH);
  mmX<0>(sm);
  s2g(ws + SL_Q, sm.S0);
}

// Xc_i = Mnh sqrt(X_i) Mnh -> out ; accumulate sum(Xc).  4 matrices/block.
__global__ __launch_bounds__(256, 3) void k1(const float* __restrict__ X,
                                             float* __restrict__ out, float* ws) {
  __shared__ SmemK sm;
  int t = threadIdx.x;
  int w = t >> 6, lane = t & 63;
  size_t b = blockIdx.x;
  g2s68(sm.Bop, ws + SL_MNH);

  float own[64]; float w2;
  {
    const float* Xm = X + (b * 4 + w) * 4096 + (size_t)lane * 64;  // row lane = col lane (symmetric)
#pragma unroll
    for (int j = 0; j < 16; ++j) {
      F4 r = *(const F4*)&Xm[4 * j];
      own[4 * j + 0] = r.v[0]; own[4 * j + 1] = r.v[1];
      own[4 * j + 2] = r.v[2]; own[4 * j + 3] = r.v[3];
    }
  }
  hestenes_reg(own, w2, SW_BATCH);
  __syncthreads();

  int R0 = t >> 4, J = (t & 15) * 4;
  for (int m = 0; m < 4; ++m) {
    if (w == m) {
#pragma unroll
      for (int j = 0; j < 16; ++j) {
        F4 o = {{own[4 * j], own[4 * j + 1], own[4 * j + 2], own[4 * j + 3]}};
        *(F4*)&sm.A[lane * NP + 4 * j] = o;
      }
      sm.wc[lane] = powf(fmaxf(w2, 1e-12f), -0.75f);   // sqrt: lam^{1/2-2}
    }
    __syncthreads();
    mm68<1>(sm.A, sm.Bop);                              // rows = lam (Mnh u)^T
    // fused recon + epilogue (no LDS round-trip)
    float acc[4][4] = {};
    for (int k = 0; k < 64; ++k) {
      float wck = sm.wc[k];
      float a[4];
#pragma unroll
      for (int i = 0; i < 4; ++i) a[i] = wck * sm.A[k * NP + R0 + 16 * i];
      F4 bb = *(const F4*)&sm.A[k * NP + J];
#pragma unroll
      for (int i = 0; i < 4; ++i)
#pragma unroll
        for (int mc = 0; mc < 4; ++mc) acc[i][mc] = fmaf(a[i], bb.v[mc], acc[i][mc]);
    }
    float* Xc = out + (b * 4 + m) * 4096;
    float* accp = ws + OFF_ACCG + (size_t)((b * 4 + m) & (NPART - 1)) * 4096;
#pragma unroll
    for (int i = 0; i < 4; ++i) {
      F4 o;
#pragma unroll
      for (int mc = 0; mc < 4; ++mc) o.v[mc] = acc[i][mc];
      int base = (R0 + 16 * i) * 64 + J;
      *(F4*)&Xc[base] = o;
#pragma unroll
      for (int mc = 0; mc < 4; ++mc) atomicAdd(accp + base + mc, o.v[mc]);
    }
    __syncthreads();
  }
}

// G0 = mean(Xc); eig -> G0h, G0nh   (unchanged, old path)
__global__ __launch_bounds__(256, 4) void ksmall2(float* ws, float invB) {
  __shared__ Smem sm;
  int t = threadIdx.x;
#pragma unroll
  for (int i = 0; i < 4; ++i) {
    int e4 = t + (i << 8);
    F4 sum = {{0.f, 0.f, 0.f, 0.f}};
    for (int p = 0; p < NPART; ++p) {
      F4 vv = *(const F4*)&ws[OFF_ACCG + p * 4096 + e4 * 4];
#pragma unroll
      for (int m = 0; m < 4; ++m) sum.v[m] += vv.v[m];
    }
#pragma unroll
    for (int m = 0; m < 4; ++m) sum.v[m] *= invB;
    *(F4*)&sm.S0[(e4 >> 4) * PITCH + (e4 & 15) * 4] = sum;
  }
  __syncthreads();
  hestenes(sm, SW_SMALL);
  if (t < 64) sm.wc[t] = powf(fmaxf(sm.w2[t], 1e-12f), -0.75f);
  reconT(sm); s2g(ws + SL_GH, sm.S1);
  if (t < 64) sm.wc[t] = powf(fmaxf(sm.w2[t], 1e-12f), -1.25f);
  reconT(sm); s2g(ws + SL_GNH, sm.S1);
}

// accumulate sum_i log(G0nh Xc_i G0nh).  4 matrices/block.
__global__ __launch_bounds__(256, 3) void k2(const float* __restrict__ XcBuf, float* ws) {
  __shared__ SmemK sm;
  int t = threadIdx.x;
  int w = t >> 6, lane = t & 63;
  size_t b = blockIdx.x;
  g2s68(sm.Bop, ws + SL_GNH);

  float own[64]; float w2;
  for (int m = 0; m < 4; ++m) {
    g2s68(sm.A, XcBuf + (b * 4 + m) * 4096);
    mm68<1>(sm.A, sm.Bop);                    // Xc*Gnh
    mm68<0>(sm.A, sm.Bop);                    // Gnh*Xc*Gnh
    if (w == m) {
#pragma unroll
      for (int i = 0; i < 64; ++i) own[i] = sm.A[i * NP + lane];
    }
    __syncthreads();
  }
  hestenes_reg(own, w2, SW_BATCH);
  __syncthreads();

  int R0 = t >> 4, J = (t & 15) * 4;
  for (int m = 0; m < 4; ++m) {
    if (w == m) {
#pragma unroll
      for (int j = 0; j < 16; ++j) {
        F4 o = {{own[4 * j], own[4 * j + 1], own[4 * j + 2], own[4 * j + 3]}};
        *(F4*)&sm.A[lane * NP + 4 * j] = o;
      }
      float s2 = fmaxf(w2, 1e-12f);
      sm.wc[lane] = 0.5f * logf(s2) / s2;     // log(lam)/lam^2
    }
    __syncthreads();
    float acc[4][4] = {};
    for (int k = 0; k < 64; ++k) {
      float wck = sm.wc[k];
      float a[4];
#pragma unroll
      for (int i = 0; i < 4; ++i) a[i] = wck * sm.A[k * NP + R0 + 16 * i];
      F4 bb = *(const F4*)&sm.A[k * NP + J];
#pragma unroll
      for (int i = 0; i < 4; ++i)
#pragma unroll
        for (int mc = 0; mc < 4; ++mc) acc[i][mc] = fmaf(a[i], bb.v[mc], acc[i][mc]);
    }
    float* accp = ws + OFF_ACCT + (size_t)((b * 4 + m) & (NPART - 1)) * 4096;
#pragma unroll
    for (int i = 0; i < 4; ++i) {
      int base = (R0 + 16 * i) * 64 + J;
#pragma unroll
      for (int mc = 0; mc < 4; ++mc) atomicAdd(accp + base + mc, acc[i][mc]);
    }
    __syncthreads();
  }
}

// Tbar = mean ; mean_G = G0h exp(Tbar) G0h ; mnh = mean_G^{-1/2}  (unchanged)
__global__ __launch_bounds__(256, 4) void ksmall3(float* ws, float invB) {
  __shared__ Smem sm;
  int t = threadIdx.x;
#pragma unroll
  for (int i = 0; i < 4; ++i) {
    int e4 = t + (i << 8);
    F4 sum = {{0.f, 0.f, 0.f, 0.f}};
    for (int p = 0; p < NPART; ++p) {
      F4 vv = *(const F4*)&ws[OFF_ACCT + p * 4096 + e4 * 4];
#pragma unroll
      for (int m = 0; m < 4; ++m) sum.v[m] += vv.v[m];
    }
#pragma unroll
    for (int m = 0; m < 4; ++m) sum.v[m] *= invB;
    *(F4*)&sm.S0[(e4 >> 4) * PITCH + (e4 & 15) * 4] = sum;
  }
  __syncthreads();
  float mu = sqrtf(frob2(sm)) + 1e-3f;
  if (t < 64) sm.S0[t * PITCH + t] += mu;
  __syncthreads();
  hestenes(sm, SW_SMALL);
  if (t < 64) {
    float s2 = fmaxf(sm.w2[t], 1e-12f);
    sm.wc[t] = expf(sqrtf(s2) - mu) / s2;
  }
  reconT(sm);
  g2s(sm.S0, ws + SL_GH);
  mmX<1>(sm);
  g2s(sm.S1, ws + SL_GH);
  mmX<1>(sm);
  hestenes(sm, SW_SMALL);
  if (t < 64) sm.wc[t] = powf(fmaxf(sm.w2[t], 1e-12f), -1.25f);
  reconT(sm); s2g(ws + SL_MNH2, sm.S1);
}

// T_i = log(mnh Xc_i mnh) (overwrites Xc) ; accumulate ||T||_F^2.  4/block.
__global__ __launch_bounds__(256, 3) void k3(float* __restrict__ buf, float* ws) {
  __shared__ SmemK sm;
  int t = threadIdx.x;
  int w = t >> 6, lane = t & 63;
  size_t b = blockIdx.x;
  g2s68(sm.Bop, ws + SL_MNH2);

  float own[64]; float w2;
  for (int m = 0; m < 4; ++m) {
    g2s68(sm.A, buf + (b * 4 + m) * 4096);
    mm68<1>(sm.A, sm.Bop);
    mm68<0>(sm.A, sm.Bop);
    if (w == m) {
#pragma unroll
      for (int i = 0; i < 64; ++i) own[i] = sm.A[i * NP + lane];
    }
    __syncthreads();
  }
  hestenes_reg(own, w2, SW_BATCH);
  __syncthreads();

  int R0 = t >> 4, J = (t & 15) * 4;
  for (int m = 0; m < 4; ++m) {
    if (w == m) {
#pragma unroll
      for (int j = 0; j < 16; ++j) {
        F4 o = {{own[4 * j], own[4 * j + 1], own[4 * j + 2], own[4 * j + 3]}};
        *(F4*)&sm.A[lane * NP + 4 * j] = o;
      }
      float s2 = fmaxf(w2, 1e-12f);
      sm.wc[lane] = 0.5f * logf(s2) / s2;
    }
    __syncthreads();
    float acc[4][4] = {};
    for (int k = 0; k < 64; ++k) {
      float wck = sm.wc[k];
      float a[4];
#pragma unroll
      for (int i = 0; i < 4; ++i) a[i] = wck * sm.A[k * NP + R0 + 16 * i];
      F4 bb = *(const F4*)&sm.A[k * NP + J];
#pragma unroll
      for (int i = 0; i < 4; ++i)
#pragma unroll
        for (int mc = 0; mc < 4; ++mc) acc[i][mc] = fmaf(a[i], bb.v[mc], acc[i][mc]);
    }
    float* Tg = buf + (b * 4 + m) * 4096;
    float ssq = 0.f;
#pragma unroll
    for (int i = 0; i < 4; ++i) {
      F4 o;
#pragma unroll
      for (int mc = 0; mc < 4; ++mc) o.v[mc] = acc[i][mc];
      int base = (R0 + 16 * i) * 64 + J;
      *(F4*)&Tg[base] = o;
#pragma unroll
      for (int mc = 0; mc < 4; ++mc) ssq = fmaf(o.v[mc], o.v[mc], ssq);
    }
    sm.red[t] = ssq;
    __syncthreads();
    for (int o = 128; o; o >>= 1) { if (t < o) sm.red[t] += sm.red[t + o]; __syncthreads(); }
    if (t == 0) atomicAdd(ws + OFF_VAR, sm.red[0]);
    __syncthreads();
  }
}

__global__ void kscale(float* ws, const float* __restrict__ shift, float invB) {
  if (threadIdx.x == 0 && blockIdx.x == 0) {
    float var = ws[OFF_VAR] * invB;
    ws[SL_SC] = shift[0] / sqrtf(var + 1e-5f);
  }
}

// Y_i = (Q exp(scale * P T_i P^T) Q^T)^2 -> buf.  4 matrices/block.
__global__ __launch_bounds__(256, 3) void k4(float* __restrict__ buf, float* ws) {
  __shared__ SmemK4 sm;
  int t = threadIdx.x;
  int w = t >> 6, lane = t & 63;
  size_t b = blockIdx.x;
  float sc = ws[SL_SC];
  g2s68(sm.P, ws + SL_P);
  g2s68(sm.Q, ws + SL_Q);

  float own[64]; float w2; float muw = 0.f;
  for (int m = 0; m < 4; ++m) {
    g2s68s(sm.A, buf + (b * 4 + m) * 4096, sc);   // scale*T
    mm68<0>(sm.A, sm.P);                          // P*(scT)
    mm68<2>(sm.A, sm.P);                          // P*(scT)*P^T (symmetric indefinite)
    float f = frob68(sm.A, sm.red);
    if (w == m) {
      muw = sqrtf(f) + 1e-3f;                     // SPD shift
#pragma unroll
      for (int i = 0; i < 64; ++i) {
        float v = sm.A[i * NP + lane];
        own[i] = v + ((i == lane) ? muw : 0.f);
      }
    }
    __syncthreads();
  }
  hestenes_reg(own, w2, SW_BATCH);
  __syncthreads();

  int R0 = t >> 4, J = (t & 15) * 4;
  for (int m = 0; m < 4; ++m) {
    if (w == m) {
#pragma unroll
      for (int j = 0; j < 16; ++j) {
        F4 o = {{own[4 * j], own[4 * j + 1], own[4 * j + 2], own[4 * j + 3]}};
        *(F4*)&sm.A[lane * NP + 4 * j] = o;
      }
      float s2 = fmaxf(w2, 1e-12f);
      sm.wc[lane] = expf(sqrtf(s2) - muw) / s2;
    }
    __syncthreads();
    mm68<2>(sm.A, sm.Q);                          // rows = lam (Q u)^T
    // recon -> sm.P (P is dead after pre-phase): Z = Q E Q^T
    float acc[4][4] = {};
    for (int k = 0; k < 64; ++k) {
      float wck = sm.wc[k];
      float a[4];
#pragma unroll
      for (int i = 0; i < 4; ++i) a[i] = wck * sm.A[k * NP + R0 + 16 * i];
      F4 bb = *(const F4*)&sm.A[k * NP + J];
#pragma unroll
      for (int i = 0; i < 4; ++i)
#pragma unroll
        for (int mc = 0; mc < 4; ++mc) acc[i][mc] = fmaf(a[i], bb.v[mc], acc[i][mc]);
    }
#pragma unroll
    for (int i = 0; i < 4; ++i) {
      F4 o;
#pragma unroll
      for (int mc = 0; mc < 4; ++mc) o.v[mc] = acc[i][mc];
      *(F4*)&sm.P[(R0 + 16 * i) * NP + J] = o;
    }
    __syncthreads();
    msq_store(sm.P, buf + (b * 4 + m) * 4096);    // Y = Z*Z -> global
    __syncthreads();
  }
}

extern "C" void kernel_launch(void* const* d_in, const int* in_sizes, int n_in,
                              void* d_out, int out_size, void* d_ws, size_t ws_size,
                              hipStream_t stream) {
  const float* X      = (const float*)d_in[0];
  const float* weight = (const float*)d_in[1];
  const float* M      = (const float*)d_in[2];
  const float* shift  = (const float*)d_in[3];
  float* out = (float*)d_out;
  float* ws  = (float*)d_ws;
  int B = in_sizes[0] / 4096;      // 4096 matrices of 64x64
  float invB = 1.f / (float)B;
  int G = B / 4;                   // 4 matrices per block

  hipLaunchKernelGGL(kzero,   dim3(OFF_BASE / 256), dim3(256), 0, stream, ws);
  hipLaunchKernelGGL(kprep,   dim3(1), dim3(256), 0, stream, weight, M, ws);
  hipLaunchKernelGGL(k1,      dim3(G), dim3(256), 0, stream, X, out, ws);
  hipLaunchKernelGGL(ksmall2, dim3(1), dim3(256), 0, stream, ws, invB);
  hipLaunchKernelGGL(k2,      dim3(G), dim3(256), 0, stream, out, ws);
  hipLaunchKernelGGL(ksmall3, dim3(1), dim3(256), 0, stream, ws, invB);
  hipLaunchKernelGGL(k3,      dim3(G), dim3(256), 0, stream, out, ws);
  hipLaunchKernelGGL(kscale,  dim3(1), dim3(64), 0, stream, ws, shift, invB);
  hipLaunchKernelGGL(k4,      dim3(G), dim3(256), 0, stream, out, ws);
}

// Round 3
// 8989.716 us; speedup vs baseline: 1.2080x; 1.0199x over previous
//
#include <hip/hip_runtime.h>
#include <math.h>

#define PITCH 72      // old layout (small kernels only)
#define NP 68         // new pitch: word(row r, col c) = 68r+c ; bank = (4r+c) mod 32
#define SW_BATCH 12
#define SW_SMALL 10
#define NPART 32
#define EPS2_ROT 1e-12f   // (1e-6)^2 : threshold compared on d^2

// ---- workspace float-offsets ----
#define OFF_ACCG 0
#define OFF_ACCT (NPART*4096)
#define OFF_BASE (2*NPART*4096)
#define SL_MNH  (OFF_BASE + 0*4096)
#define SL_MH   (OFF_BASE + 1*4096)
#define SL_WH   (OFF_BASE + 2*4096)
#define SL_P    (OFF_BASE + 3*4096)
#define SL_Q    (OFF_BASE + 4*4096)
#define SL_GH   (OFF_BASE + 5*4096)
#define SL_GNH  (OFF_BASE + 6*4096)
#define SL_MNH2 (OFF_BASE + 7*4096)
#define SL_WCH  (OFF_BASE + 8*4096)
#define OFF_VAR (OFF_BASE + 9*4096)
#define SL_SC   (OFF_BASE + 9*4096 + 1)

struct __align__(16) F4 { float v[4]; };

// ======================================================================
// OLD infrastructure (PITCH 72) — used only by the 1-block small kernels
// ======================================================================
struct __align__(16) Smem {
  float S0[64*PITCH];
  float S1[64*PITCH];
  float w2[64];
  float wc[64];
  float nrm[64];
  float red[256];
  int flag;
};

__device__ __forceinline__ void g2s(float* dst, const float* __restrict__ src) {
  int t = threadIdx.x;
#pragma unroll
  for (int i = 0; i < 4; ++i) {
    int e4 = t + (i << 8);
    F4 vv = *(const F4*)&src[e4 * 4];
    *(F4*)&dst[(e4 >> 4) * PITCH + (e4 & 15) * 4] = vv;
  }
  __syncthreads();
}
__device__ __forceinline__ void s2g(float* __restrict__ dst, const float* src) {
  int t = threadIdx.x;
#pragma unroll
  for (int i = 0; i < 4; ++i) {
    int e4 = t + (i << 8);
    F4 vv = *(const F4*)&src[(e4 >> 4) * PITCH + (e4 & 15) * 4];
    *(F4*)&dst[e4 * 4] = vv;
  }
  __syncthreads();
}

template<int MODE>   // 0: S0<-S1*S0 ; 1: S0<-S0*S1
__device__ void mmX(Smem& sm) {
  int t = threadIdx.x;
  int R0 = t >> 4;
  int J = (t & 15) * 4;
  float acc[4][4] = {};
  for (int kb = 0; kb < 64; kb += 4) {
    F4 a4[4], b4[4];
#pragma unroll
    for (int i = 0; i < 4; ++i) {
      const float* L = (MODE == 0) ? sm.S1 : sm.S0;
      a4[i] = *(const F4*)&L[(R0 + 16 * i) * PITCH + kb];
    }
#pragma unroll
    for (int kk = 0; kk < 4; ++kk) {
      const float* Rp = (MODE == 0) ? sm.S0 : sm.S1;
      b4[kk] = *(const F4*)&Rp[(kb + kk) * PITCH + J];
    }
#pragma unroll
    for (int i = 0; i < 4; ++i)
#pragma unroll
      for (int kk = 0; kk < 4; ++kk)
#pragma unroll
        for (int m = 0; m < 4; ++m)
          acc[i][m] = fmaf(a4[i].v[kk], b4[kk].v[m], acc[i][m]);
  }
  __syncthreads();
#pragma unroll
  for (int i = 0; i < 4; ++i) {
    F4 o;
#pragma unroll
    for (int m = 0; m < 4; ++m) o.v[m] = acc[i][m];
    *(F4*)&sm.S0[(R0 + 16 * i) * PITCH + J] = o;
  }
  __syncthreads();
}

__device__ void reconT(Smem& sm) {
  __syncthreads();
  int t = threadIdx.x;
  int R0 = t >> 4;
  int J = (t & 15) * 4;
  float acc[4][4] = {};
  for (int k = 0; k < 64; ++k) {
    float w = sm.wc[k];
    float a[4];
#pragma unroll
    for (int i = 0; i < 4; ++i) a[i] = w * sm.S0[k * PITCH + R0 + 16 * i];
    F4 b = *(const F4*)&sm.S0[k * PITCH + J];
#pragma unroll
    for (int i = 0; i < 4; ++i)
#pragma unroll
      for (int m = 0; m < 4; ++m) acc[i][m] = fmaf(a[i], b.v[m], acc[i][m]);
  }
#pragma unroll
  for (int i = 0; i < 4; ++i) {
    F4 o;
#pragma unroll
    for (int m = 0; m < 4; ++m) o.v[m] = acc[i][m];
    *(F4*)&sm.S1[(R0 + 16 * i) * PITCH + J] = o;
  }
  __syncthreads();
}

__device__ float frob2(Smem& sm) {
  int t = threadIdx.x;
  float s = 0.f;
#pragma unroll
  for (int i = 0; i < 4; ++i) {
    int e4 = t + (i << 8);
    F4 vv = *(const F4*)&sm.S0[(e4 >> 4) * PITCH + (e4 & 15) * 4];
#pragma unroll
    for (int m = 0; m < 4; ++m) s = fmaf(vv.v[m], vv.v[m], s);
  }
  sm.red[t] = s;
  __syncthreads();
  for (int o = 128; o; o >>= 1) { if (t < o) sm.red[t] += sm.red[t + o]; __syncthreads(); }
  float f = sm.red[0];
  __syncthreads();
  return f;
}

__device__ void hestenes(Smem& sm, int sweeps) {
  const int t = threadIdx.x;
  const int g = t >> 3;
  const int u = t & 7;
  float* A = sm.S0;
  {
    float sa = 0.f, sb = 0.f;
#pragma unroll
    for (int i = 0; i < 8; ++i) {
      float va = A[g * PITCH + u + 8 * i];
      float vb = A[(g + 32) * PITCH + u + 8 * i];
      sa = fmaf(va, va, sa); sb = fmaf(vb, vb, sb);
    }
    sa += __shfl_xor(sa, 1); sa += __shfl_xor(sa, 2); sa += __shfl_xor(sa, 4);
    sb += __shfl_xor(sb, 1); sb += __shfl_xor(sb, 2); sb += __shfl_xor(sb, 4);
    if (u == 0) { sm.nrm[g] = sa; sm.nrm[g + 32] = sb; }
    if (t == 0) sm.flag = 0;
  }
  __syncthreads();

  for (int s = 0; s < sweeps; ++s) {
    for (int r = 0; r < 63; ++r) {
      int p, q;
      if (g == 0) { p = 63; q = r; }
      else {
        int a = r + g;      if (a >= 63) a -= 63;
        int b = r + 63 - g; if (b >= 63) b -= 63;
        p = a; q = b;
      }
      const int bp = p * PITCH + u, bq = q * PITCH + u;
      float cp[8], cq[8];
#pragma unroll
      for (int i = 0; i < 8; ++i) { cp[i] = A[bp + 8 * i]; cq[i] = A[bq + 8 * i]; }
      float d = 0.f;
#pragma unroll
      for (int i = 0; i < 8; ++i) d = fmaf(cp[i], cq[i], d);
      d += __shfl_xor(d, 1); d += __shfl_xor(d, 2); d += __shfl_xor(d, 4);
      float dpp = sm.nrm[p], dqq = sm.nrm[q];
      if (d * d > EPS2_ROT * (dpp * dqq)) {
        float tau = (dqq - dpp) * (0.5f * __builtin_amdgcn_rcpf(d));
        float tt = __builtin_amdgcn_rcpf(fabsf(tau) +
                                         __builtin_amdgcn_sqrtf(fmaf(tau, tau, 1.f)));
        if (tau < 0.f) tt = -tt;
        float c = __builtin_amdgcn_rsqf(fmaf(tt, tt, 1.f));
        float s_ = tt * c;
#pragma unroll
        for (int i = 0; i < 8; ++i) {
          A[bp + 8 * i] = c * cp[i] - s_ * cq[i];
          A[bq + 8 * i] = s_ * cp[i] + c * cq[i];
        }
        if (u == 0) {
          float td = tt * d;
          sm.nrm[p] = dpp - td;
          sm.nrm[q] = dqq + td;
          sm.flag = 1;
        }
      }
      __syncthreads();
    }
    int f = sm.flag;
    __syncthreads();
    if (f == 0) break;
    if (t == 0) sm.flag = 0;
    __syncthreads();
  }

  {
    float sa = 0.f, sb = 0.f;
#pragma unroll
    for (int i = 0; i < 8; ++i) {
      float va = A[g * PITCH + u + 8 * i];
      float vb = A[(g + 32) * PITCH + u + 8 * i];
      sa = fmaf(va, va, sa); sb = fmaf(vb, vb, sb);
    }
    sa += __shfl_xor(sa, 1); sa += __shfl_xor(sa, 2); sa += __shfl_xor(sa, 4);
    sb += __shfl_xor(sb, 1); sb += __shfl_xor(sb, 2); sb += __shfl_xor(sb, 4);
    if (u == 0) { sm.w2[g] = sa; sm.w2[g + 32] = sb; }
  }
  __syncthreads();
}

// ======================================================================
// NEW infrastructure (pitch 68) — batch kernels, 4 matrices per block
// ======================================================================
struct __align__(16) SmemK {      // k1,k2,k3 : 36.1 KB
  float A[64*NP];
  float Bop[64*NP];
  float wc[64];
  float red[256];
};
struct __align__(16) SmemK4 {     // k4 : 52.3 KB
  float A[64*NP];
  float P[64*NP];
  float Q[64*NP];
  float wc[64];
  float red[256];
};

__device__ __forceinline__ void g2s68(float* dst, const float* __restrict__ src) {
  int t = threadIdx.x;
#pragma unroll
  for (int i = 0; i < 4; ++i) {
    int e4 = t + (i << 8);
    F4 vv = *(const F4*)&src[e4 * 4];
    *(F4*)&dst[(e4 >> 4) * NP + (e4 & 15) * 4] = vv;
  }
  __syncthreads();
}
__device__ __forceinline__ void g2s68s(float* dst, const float* __restrict__ src, float sc) {
  int t = threadIdx.x;
#pragma unroll
  for (int i = 0; i < 4; ++i) {
    int e4 = t + (i << 8);
    F4 vv = *(const F4*)&src[e4 * 4];
#pragma unroll
    for (int m = 0; m < 4; ++m) vv.v[m] *= sc;
    *(F4*)&dst[(e4 >> 4) * NP + (e4 & 15) * 4] = vv;
  }
  __syncthreads();
}

// MODE 0: A <- Bo*A ; 1: A <- A*Bo ; 2: A <- A*Bo^T   (all in-place on A)
template<int MODE>
__device__ void mm68(float* A, const float* Bo) {
  int t = threadIdx.x;
  int R0 = t >> 4;
  if (MODE == 2) {
    int J0 = t & 15;
    float acc[4][4] = {};
    for (int kb = 0; kb < 64; kb += 4) {
      F4 a4[4];
#pragma unroll
      for (int i = 0; i < 4; ++i) a4[i] = *(const F4*)&A[(R0 + 16 * i) * NP + kb];
#pragma unroll
      for (int kk = 0; kk < 4; ++kk) {
        float b[4];
#pragma unroll
        for (int m = 0; m < 4; ++m) b[m] = Bo[(J0 + 16 * m) * NP + kb + kk];
#pragma unroll
        for (int i = 0; i < 4; ++i)
#pragma unroll
          for (int m = 0; m < 4; ++m) acc[i][m] = fmaf(a4[i].v[kk], b[m], acc[i][m]);
      }
    }
    __syncthreads();
#pragma unroll
    for (int i = 0; i < 4; ++i)
#pragma unroll
      for (int m = 0; m < 4; ++m)
        A[(R0 + 16 * i) * NP + J0 + 16 * m] = acc[i][m];
    __syncthreads();
  } else {
    int J = (t & 15) * 4;
    float acc[4][4] = {};
    for (int kb = 0; kb < 64; kb += 4) {
      F4 a4[4], b4[4];
#pragma unroll
      for (int i = 0; i < 4; ++i) {
        const float* L = (MODE == 0) ? Bo : A;
        a4[i] = *(const F4*)&L[(R0 + 16 * i) * NP + kb];
      }
#pragma unroll
      for (int kk = 0; kk < 4; ++kk) {
        const float* Rp = (MODE == 0) ? A : Bo;
        b4[kk] = *(const F4*)&Rp[(kb + kk) * NP + J];
      }
#pragma unroll
      for (int i = 0; i < 4; ++i)
#pragma unroll
        for (int kk = 0; kk < 4; ++kk)
#pragma unroll
          for (int m = 0; m < 4; ++m)
            acc[i][m] = fmaf(a4[i].v[kk], b4[kk].v[m], acc[i][m]);
    }
    __syncthreads();
#pragma unroll
    for (int i = 0; i < 4; ++i) {
      F4 o;
#pragma unroll
      for (int m = 0; m < 4; ++m) o.v[m] = acc[i][m];
      *(F4*)&A[(R0 + 16 * i) * NP + J] = o;
    }
    __syncthreads();
  }
}

__device__ float frob68(const float* A, float* red) {
  int t = threadIdx.x;
  float s = 0.f;
#pragma unroll
  for (int i = 0; i < 4; ++i) {
    int e4 = t + (i << 8);
    F4 vv = *(const F4*)&A[(e4 >> 4) * NP + (e4 & 15) * 4];
#pragma unroll
    for (int m = 0; m < 4; ++m) s = fmaf(vv.v[m], vv.v[m], s);
  }
  red[t] = s;
  __syncthreads();
  for (int o = 128; o; o >>= 1) { if (t < o) red[t] += red[t + o]; __syncthreads(); }
  float f = red[0];
  __syncthreads();
  return f;
}

// Z*Z -> global (row-major 64x64), reads Z (pitch 68), no LDS writes
__device__ void msq_store(const float* Z, float* __restrict__ gout) {
  int t = threadIdx.x;
  int R0 = t >> 4;
  int J = (t & 15) * 4;
  float acc[4][4] = {};
  for (int kb = 0; kb < 64; kb += 4) {
    F4 a4[4], b4[4];
#pragma unroll
    for (int i = 0; i < 4; ++i) a4[i] = *(const F4*)&Z[(R0 + 16 * i) * NP + kb];
#pragma unroll
    for (int kk = 0; kk < 4; ++kk) b4[kk] = *(const F4*)&Z[(kb + kk) * NP + J];
#pragma unroll
    for (int i = 0; i < 4; ++i)
#pragma unroll
      for (int kk = 0; kk < 4; ++kk)
#pragma unroll
        for (int m = 0; m < 4; ++m)
          acc[i][m] = fmaf(a4[i].v[kk], b4[kk].v[m], acc[i][m]);
  }
#pragma unroll
  for (int i = 0; i < 4; ++i) {
    F4 o;
#pragma unroll
    for (int m = 0; m < 4; ++m) o.v[m] = acc[i][m];
    *(F4*)&gout[(R0 + 16 * i) * 64 + J] = o;
  }
}

// ---------- register-resident wave-synchronous one-sided Jacobi ----------
// lane l holds column l (= row l of the symmetric input) in own[64].
// XOR ordering: round m pairs lane l with lane l^m (m=1..63) — each column
// pair exactly once per sweep. Both lanes of a pair compute bitwise-identical
// d / rotation params (products commute), so no reduce/broadcast is needed.
// No LDS, no barriers; convergence via wave-level __any.
// REQUIRES ~150+ VGPRs live (own + pv): kernels using this must declare
// __launch_bounds__(256, 1) so the allocator doesn't spill pv to scratch
// (R2 post-mortem: (256,3) capped VGPR at 84 -> scratch traffic dominated).
__device__ __forceinline__ void hestenes_reg(float (&own)[64], float& w2out, int sweeps) {
  const int lane = threadIdx.x & 63;
  float nrm = 0.f;
#pragma unroll
  for (int i = 0; i < 64; ++i) nrm = fmaf(own[i], own[i], nrm);

  for (int s = 0; s < sweeps; ++s) {
    bool any = false;
    for (int m = 1; m < 64; ++m) {
      float pv[64];
#pragma unroll
      for (int i = 0; i < 64; ++i) pv[i] = __shfl_xor(own[i], m);
      float d0 = 0.f, d1 = 0.f, d2 = 0.f, d3 = 0.f;
#pragma unroll
      for (int i = 0; i < 64; i += 4) {
        d0 = fmaf(own[i + 0], pv[i + 0], d0);
        d1 = fmaf(own[i + 1], pv[i + 1], d1);
        d2 = fmaf(own[i + 2], pv[i + 2], d2);
        d3 = fmaf(own[i + 3], pv[i + 3], d3);
      }
      float d = (d0 + d1) + (d2 + d3);
      float pn = __shfl_xor(nrm, m);
      if (d * d > EPS2_ROT * (nrm * pn)) {     // pair-uniform (bitwise-symmetric)
        any = true;
        bool lo = lane < (lane ^ m);           // exactly one lane of the pair
        float dpp = lo ? nrm : pn;
        float dqq = lo ? pn : nrm;
        float tau = (dqq - dpp) * (0.5f * __builtin_amdgcn_rcpf(d));
        float tt = __builtin_amdgcn_rcpf(fabsf(tau) +
                                         __builtin_amdgcn_sqrtf(fmaf(tau, tau, 1.f)));
        if (tau < 0.f) tt = -tt;
        float c = __builtin_amdgcn_rsqf(fmaf(tt, tt, 1.f));
        float s_ = tt * c;
        float sg = lo ? -s_ : s_;              // lo: c*p - s*q ; hi: c*q + s*p
#pragma unroll
        for (int i = 0; i < 64; ++i) own[i] = fmaf(sg, pv[i], c * own[i]);
        float td = tt * d;
        nrm += lo ? -td : td;                  // exact Jacobi diagonal update
      }
    }
    if (!__any((int)any)) break;
  }
  float w = 0.f;
#pragma unroll
  for (int i = 0; i < 64; ++i) w = fmaf(own[i], own[i], w);
  w2out = w;
}

// ============================ kernels ============================

__global__ __launch_bounds__(256) void kzero(float* ws) {
  int i = blockIdx.x * 256 + threadIdx.x;
  if (i < OFF_BASE) ws[i] = 0.f;
  if (i == 0) ws[OFF_VAR] = 0.f;
}

// Mnh/Mh/Wh/Wc-eig -> P = Wc^{-1/2} Wh, Q = Mh Wc^{1/2}   (unchanged, old path)
__global__ __launch_bounds__(256, 4) void kprep(const float* __restrict__ weight,
                                                const float* __restrict__ M,
                                                float* ws) {
  __shared__ Smem sm;
  int t = threadIdx.x;
  g2s(sm.S0, M);
  hestenes(sm, SW_SMALL);
  if (t < 64) sm.wc[t] = powf(fmaxf(sm.w2[t], 1e-12f), -1.25f);
  reconT(sm); s2g(ws + SL_MNH, sm.S1);
  if (t < 64) sm.wc[t] = powf(fmaxf(sm.w2[t], 1e-12f), -0.75f);
  reconT(sm); s2g(ws + SL_MH, sm.S1);

  g2s(sm.S0, weight);
  hestenes(sm, SW_SMALL);
  if (t < 64) sm.wc[t] = powf(fmaxf(sm.w2[t], 1e-12f), -0.75f);
  reconT(sm); s2g(ws + SL_WH, sm.S1);

  g2s(sm.S0, ws + SL_MNH);
  mmX<1>(sm);
  g2s(sm.S1, ws + SL_MNH);
  mmX<1>(sm);
  hestenes(sm, SW_SMALL);
  if (t < 64) sm.wc[t] = powf(fmaxf(sm.w2[t], 1e-12f), -0.75f);
  reconT(sm); s2g(ws + SL_WCH, sm.S1);
  if (t < 64) sm.wc[t] = powf(fmaxf(sm.w2[t], 1e-12f), -1.25f);
  reconT(sm);
  g2s(sm.S0, ws + SL_WH);
  mmX<0>(sm);
  s2g(ws + SL_P, sm.S0);
  g2s(sm.S0, ws + SL_WCH);
  g2s(sm.S1, ws + SL_MH);
  mmX<0>(sm);
  s2g(ws + SL_Q, sm.S0);
}

// Xc_i = Mnh sqrt(X_i) Mnh -> out ; accumulate sum(Xc).  4 matrices/block.
__global__ __launch_bounds__(256, 1) void k1(const float* __restrict__ X,
                                             float* __restrict__ out, float* ws) {
  __shared__ SmemK sm;
  int t = threadIdx.x;
  int w = t >> 6, lane = t & 63;
  size_t b = blockIdx.x;
  g2s68(sm.Bop, ws + SL_MNH);

  float own[64]; float w2;
  {
    const float* Xm = X + (b * 4 + w) * 4096 + (size_t)lane * 64;  // row lane = col lane (symmetric)
#pragma unroll
    for (int j = 0; j < 16; ++j) {
      F4 r = *(const F4*)&Xm[4 * j];
      own[4 * j + 0] = r.v[0]; own[4 * j + 1] = r.v[1];
      own[4 * j + 2] = r.v[2]; own[4 * j + 3] = r.v[3];
    }
  }
  hestenes_reg(own, w2, SW_BATCH);
  __syncthreads();

  int R0 = t >> 4, J = (t & 15) * 4;
  for (int m = 0; m < 4; ++m) {
    if (w == m) {
#pragma unroll
      for (int j = 0; j < 16; ++j) {
        F4 o = {{own[4 * j], own[4 * j + 1], own[4 * j + 2], own[4 * j + 3]}};
        *(F4*)&sm.A[lane * NP + 4 * j] = o;
      }
      sm.wc[lane] = powf(fmaxf(w2, 1e-12f), -0.75f);   // sqrt: lam^{1/2-2}
    }
    __syncthreads();
    mm68<1>(sm.A, sm.Bop);                              // rows = lam (Mnh u)^T
    // fused recon + epilogue (no LDS round-trip)
    float acc[4][4] = {};
    for (int k = 0; k < 64; ++k) {
      float wck = sm.wc[k];
      float a[4];
#pragma unroll
      for (int i = 0; i < 4; ++i) a[i] = wck * sm.A[k * NP + R0 + 16 * i];
      F4 bb = *(const F4*)&sm.A[k * NP + J];
#pragma unroll
      for (int i = 0; i < 4; ++i)
#pragma unroll
        for (int mc = 0; mc < 4; ++mc) acc[i][mc] = fmaf(a[i], bb.v[mc], acc[i][mc]);
    }
    float* Xc = out + (b * 4 + m) * 4096;
    float* accp = ws + OFF_ACCG + (size_t)((b * 4 + m) & (NPART - 1)) * 4096;
#pragma unroll
    for (int i = 0; i < 4; ++i) {
      F4 o;
#pragma unroll
      for (int mc = 0; mc < 4; ++mc) o.v[mc] = acc[i][mc];
      int base = (R0 + 16 * i) * 64 + J;
      *(F4*)&Xc[base] = o;
#pragma unroll
      for (int mc = 0; mc < 4; ++mc) atomicAdd(accp + base + mc, o.v[mc]);
    }
    __syncthreads();
  }
}

// G0 = mean(Xc); eig -> G0h, G0nh   (unchanged, old path)
__global__ __launch_bounds__(256, 4) void ksmall2(float* ws, float invB) {
  __shared__ Smem sm;
  int t = threadIdx.x;
#pragma unroll
  for (int i = 0; i < 4; ++i) {
    int e4 = t + (i << 8);
    F4 sum = {{0.f, 0.f, 0.f, 0.f}};
    for (int p = 0; p < NPART; ++p) {
      F4 vv = *(const F4*)&ws[OFF_ACCG + p * 4096 + e4 * 4];
#pragma unroll
      for (int m = 0; m < 4; ++m) sum.v[m] += vv.v[m];
    }
#pragma unroll
    for (int m = 0; m < 4; ++m) sum.v[m] *= invB;
    *(F4*)&sm.S0[(e4 >> 4) * PITCH + (e4 & 15) * 4] = sum;
  }
  __syncthreads();
  hestenes(sm, SW_SMALL);
  if (t < 64) sm.wc[t] = powf(fmaxf(sm.w2[t], 1e-12f), -0.75f);
  reconT(sm); s2g(ws + SL_GH, sm.S1);
  if (t < 64) sm.wc[t] = powf(fmaxf(sm.w2[t], 1e-12f), -1.25f);
  reconT(sm); s2g(ws + SL_GNH, sm.S1);
}

// accumulate sum_i log(G0nh Xc_i G0nh).  4 matrices/block.
__global__ __launch_bounds__(256, 1) void k2(const float* __restrict__ XcBuf, float* ws) {
  __shared__ SmemK sm;
  int t = threadIdx.x;
  int w = t >> 6, lane = t & 63;
  size_t b = blockIdx.x;
  g2s68(sm.Bop, ws + SL_GNH);

  float own[64]; float w2;
  for (int m = 0; m < 4; ++m) {
    g2s68(sm.A, XcBuf + (b * 4 + m) * 4096);
    mm68<1>(sm.A, sm.Bop);                    // Xc*Gnh
    mm68<0>(sm.A, sm.Bop);                    // Gnh*Xc*Gnh
    if (w == m) {
#pragma unroll
      for (int i = 0; i < 64; ++i) own[i] = sm.A[i * NP + lane];
    }
    __syncthreads();
  }
  hestenes_reg(own, w2, SW_BATCH);
  __syncthreads();

  int R0 = t >> 4, J = (t & 15) * 4;
  for (int m = 0; m < 4; ++m) {
    if (w == m) {
#pragma unroll
      for (int j = 0; j < 16; ++j) {
        F4 o = {{own[4 * j], own[4 * j + 1], own[4 * j + 2], own[4 * j + 3]}};
        *(F4*)&sm.A[lane * NP + 4 * j] = o;
      }
      float s2 = fmaxf(w2, 1e-12f);
      sm.wc[lane] = 0.5f * logf(s2) / s2;     // log(lam)/lam^2
    }
    __syncthreads();
    float acc[4][4] = {};
    for (int k = 0; k < 64; ++k) {
      float wck = sm.wc[k];
      float a[4];
#pragma unroll
      for (int i = 0; i < 4; ++i) a[i] = wck * sm.A[k * NP + R0 + 16 * i];
      F4 bb = *(const F4*)&sm.A[k * NP + J];
#pragma unroll
      for (int i = 0; i < 4; ++i)
#pragma unroll
        for (int mc = 0; mc < 4; ++mc) acc[i][mc] = fmaf(a[i], bb.v[mc], acc[i][mc]);
    }
    float* accp = ws + OFF_ACCT + (size_t)((b * 4 + m) & (NPART - 1)) * 4096;
#pragma unroll
    for (int i = 0; i < 4; ++i) {
      int base = (R0 + 16 * i) * 64 + J;
#pragma unroll
      for (int mc = 0; mc < 4; ++mc) atomicAdd(accp + base + mc, acc[i][mc]);
    }
    __syncthreads();
  }
}

// Tbar = mean ; mean_G = G0h exp(Tbar) G0h ; mnh = mean_G^{-1/2}  (unchanged)
__global__ __launch_bounds__(256, 4) void ksmall3(float* ws, float invB) {
  __shared__ Smem sm;
  int t = threadIdx.x;
#pragma unroll
  for (int i = 0; i < 4; ++i) {
    int e4 = t + (i << 8);
    F4 sum = {{0.f, 0.f, 0.f, 0.f}};
    for (int p = 0; p < NPART; ++p) {
      F4 vv = *(const F4*)&ws[OFF_ACCT + p * 4096 + e4 * 4];
#pragma unroll
      for (int m = 0; m < 4; ++m) sum.v[m] += vv.v[m];
    }
#pragma unroll
    for (int m = 0; m < 4; ++m) sum.v[m] *= invB;
    *(F4*)&sm.S0[(e4 >> 4) * PITCH + (e4 & 15) * 4] = sum;
  }
  __syncthreads();
  float mu = sqrtf(frob2(sm)) + 1e-3f;
  if (t < 64) sm.S0[t * PITCH + t] += mu;
  __syncthreads();
  hestenes(sm, SW_SMALL);
  if (t < 64) {
    float s2 = fmaxf(sm.w2[t], 1e-12f);
    sm.wc[t] = expf(sqrtf(s2) - mu) / s2;
  }
  reconT(sm);
  g2s(sm.S0, ws + SL_GH);
  mmX<1>(sm);
  g2s(sm.S1, ws + SL_GH);
  mmX<1>(sm);
  hestenes(sm, SW_SMALL);
  if (t < 64) sm.wc[t] = powf(fmaxf(sm.w2[t], 1e-12f), -1.25f);
  reconT(sm); s2g(ws + SL_MNH2, sm.S1);
}

// T_i = log(mnh Xc_i mnh) (overwrites Xc) ; accumulate ||T||_F^2.  4/block.
__global__ __launch_bounds__(256, 1) void k3(float* __restrict__ buf, float* ws) {
  __shared__ SmemK sm;
  int t = threadIdx.x;
  int w = t >> 6, lane = t & 63;
  size_t b = blockIdx.x;
  g2s68(sm.Bop, ws + SL_MNH2);

  float own[64]; float w2;
  for (int m = 0; m < 4; ++m) {
    g2s68(sm.A, buf + (b * 4 + m) * 4096);
    mm68<1>(sm.A, sm.Bop);
    mm68<0>(sm.A, sm.Bop);
    if (w == m) {
#pragma unroll
      for (int i = 0; i < 64; ++i) own[i] = sm.A[i * NP + lane];
    }
    __syncthreads();
  }
  hestenes_reg(own, w2, SW_BATCH);
  __syncthreads();

  int R0 = t >> 4, J = (t & 15) * 4;
  for (int m = 0; m < 4; ++m) {
    if (w == m) {
#pragma unroll
      for (int j = 0; j < 16; ++j) {
        F4 o = {{own[4 * j], own[4 * j + 1], own[4 * j + 2], own[4 * j + 3]}};
        *(F4*)&sm.A[lane * NP + 4 * j] = o;
      }
      float s2 = fmaxf(w2, 1e-12f);
      sm.wc[lane] = 0.5f * logf(s2) / s2;
    }
    __syncthreads();
    float acc[4][4] = {};
    for (int k = 0; k < 64; ++k) {
      float wck = sm.wc[k];
      float a[4];
#pragma unroll
      for (int i = 0; i < 4; ++i) a[i] = wck * sm.A[k * NP + R0 + 16 * i];
      F4 bb = *(const F4*)&sm.A[k * NP + J];
#pragma unroll
      for (int i = 0; i < 4; ++i)
#pragma unroll
        for (int mc = 0; mc < 4; ++mc) acc[i][mc] = fmaf(a[i], bb.v[mc], acc[i][mc]);
    }
    float* Tg = buf + (b * 4 + m) * 4096;
    float ssq = 0.f;
#pragma unroll
    for (int i = 0; i < 4; ++i) {
      F4 o;
#pragma unroll
      for (int mc = 0; mc < 4; ++mc) o.v[mc] = acc[i][mc];
      int base = (R0 + 16 * i) * 64 + J;
      *(F4*)&Tg[base] = o;
#pragma unroll
      for (int mc = 0; mc < 4; ++mc) ssq = fmaf(o.v[mc], o.v[mc], ssq);
    }
    sm.red[t] = ssq;
    __syncthreads();
    for (int o = 128; o; o >>= 1) { if (t < o) sm.red[t] += sm.red[t + o]; __syncthreads(); }
    if (t == 0) atomicAdd(ws + OFF_VAR, sm.red[0]);
    __syncthreads();
  }
}

__global__ void kscale(float* ws, const float* __restrict__ shift, float invB) {
  if (threadIdx.x == 0 && blockIdx.x == 0) {
    float var = ws[OFF_VAR] * invB;
    ws[SL_SC] = shift[0] / sqrtf(var + 1e-5f);
  }
}

// Y_i = (Q exp(scale * P T_i P^T) Q^T)^2 -> buf.  4 matrices/block.
__global__ __launch_bounds__(256, 1) void k4(float* __restrict__ buf, float* ws) {
  __shared__ SmemK4 sm;
  int t = threadIdx.x;
  int w = t >> 6, lane = t & 63;
  size_t b = blockIdx.x;
  float sc = ws[SL_SC];
  g2s68(sm.P, ws + SL_P);
  g2s68(sm.Q, ws + SL_Q);

  float own[64]; float w2; float muw = 0.f;
  for (int m = 0; m < 4; ++m) {
    g2s68s(sm.A, buf + (b * 4 + m) * 4096, sc);   // scale*T
    mm68<0>(sm.A, sm.P);                          // P*(scT)
    mm68<2>(sm.A, sm.P);                          // P*(scT)*P^T (symmetric indefinite)
    float f = frob68(sm.A, sm.red);
    if (w == m) {
      muw = sqrtf(f) + 1e-3f;                     // SPD shift
#pragma unroll
      for (int i = 0; i < 64; ++i) {
        float v = sm.A[i * NP + lane];
        own[i] = v + ((i == lane) ? muw : 0.f);
      }
    }
    __syncthreads();
  }
  hestenes_reg(own, w2, SW_BATCH);
  __syncthreads();

  int R0 = t >> 4, J = (t & 15) * 4;
  for (int m = 0; m < 4; ++m) {
    if (w == m) {
#pragma unroll
      for (int j = 0; j < 16; ++j) {
        F4 o = {{own[4 * j], own[4 * j + 1], own[4 * j + 2], own[4 * j + 3]}};
        *(F4*)&sm.A[lane * NP + 4 * j] = o;
      }
      float s2 = fmaxf(w2, 1e-12f);
      sm.wc[lane] = expf(sqrtf(s2) - muw) / s2;
    }
    __syncthreads();
    mm68<2>(sm.A, sm.Q);                          // rows = lam (Q u)^T
    // recon -> sm.P (P is dead after pre-phase): Z = Q E Q^T
    float acc[4][4] = {};
    for (int k = 0; k < 64; ++k) {
      float wck = sm.wc[k];
      float a[4];
#pragma unroll
      for (int i = 0; i < 4; ++i) a[i] = wck * sm.A[k * NP + R0 + 16 * i];
      F4 bb = *(const F4*)&sm.A[k * NP + J];
#pragma unroll
      for (int i = 0; i < 4; ++i)
#pragma unroll
        for (int mc = 0; mc < 4; ++mc) acc[i][mc] = fmaf(a[i], bb.v[mc], acc[i][mc]);
    }
#pragma unroll
    for (int i = 0; i < 4; ++i) {
      F4 o;
#pragma unroll
      for (int mc = 0; mc < 4; ++mc) o.v[mc] = acc[i][mc];
      *(F4*)&sm.P[(R0 + 16 * i) * NP + J] = o;
    }
    __syncthreads();
    msq_store(sm.P, buf + (b * 4 + m) * 4096);    // Y = Z*Z -> global
    __syncthreads();
  }
}

extern "C" void kernel_launch(void* const* d_in, const int* in_sizes, int n_in,
                              void* d_out, int out_size, void* d_ws, size_t ws_size,
                              hipStream_t stream) {
  const float* X      = (const float*)d_in[0];
  const float* weight = (const float*)d_in[1];
  const float* M      = (const float*)d_in[2];
  const float* shift  = (const float*)d_in[3];
  float* out = (float*)d_out;
  float* ws  = (float*)d_ws;
  int B = in_sizes[0] / 4096;      // 4096 matrices of 64x64
  float invB = 1.f / (float)B;
  int G = B / 4;                   // 4 matrices per block

  hipLaunchKernelGGL(kzero,   dim3(OFF_BASE / 256), dim3(256), 0, stream, ws);
  hipLaunchKernelGGL(kprep,   dim3(1), dim3(256), 0, stream, weight, M, ws);
  hipLaunchKernelGGL(k1,      dim3(G), dim3(256), 0, stream, X, out, ws);
  hipLaunchKernelGGL(ksmall2, dim3(1), dim3(256), 0, stream, ws, invB);
  hipLaunchKernelGGL(k2,      dim3(G), dim3(256), 0, stream, out, ws);
  hipLaunchKernelGGL(ksmall3, dim3(1), dim3(256), 0, stream, ws, invB);
  hipLaunchKernelGGL(k3,      dim3(G), dim3(256), 0, stream, out, ws);
  hipLaunchKernelGGL(kscale,  dim3(1), dim3(64), 0, stream, ws, shift, invB);
  hipLaunchKernelGGL(k4,      dim3(G), dim3(256), 0, stream, out, ws);
}